// Round 14
// baseline (344.714 us; speedup 1.0000x reference)
//
#include <hip/hip_runtime.h>

typedef __attribute__((ext_vector_type(8))) short bf16x8;
typedef __attribute__((ext_vector_type(4))) float f32x4;

__device__ __forceinline__ unsigned short f2bf(float f){
  unsigned u = __builtin_bit_cast(unsigned, f);
  u += 0x7fffu + ((u >> 16) & 1u);
  return (unsigned short)(u >> 16);
}

__device__ __forceinline__ unsigned cvt_pk_bf16(float lo, float hi){
  unsigned r;
  asm("v_cvt_pk_bf16_f32 %0, %1, %2" : "=v"(r) : "v"(lo), "v"(hi));
  return r;
}

#define ASYNC16(ldsp, gp) __builtin_amdgcn_global_load_lds( \
    (const __attribute__((address_space(1))) unsigned int*)(gp), \
    (__attribute__((address_space(3))) unsigned int*)(ldsp), 16, 0, 0)

// ---- fused prep: x fp32 -> bf16 window-ordered; weights -> bf16 FRAGMENT-MAJOR
// (Wf[bw][t][tj][lane][8]: element = W[bw*64+tj*16+(lane&15)][t*32+(lane>>4)*8+e]
//  -- a wave's B-fragment load is one coalesced 64x16B line);  bias table.
// blockIdx: [0,37632) x;  [37632,37920) weights (73728 thr: 55296 qkv panels
// 18x12x4x64, 18432 out panels 6x12x4x64);  [37920,37968) btab.
__global__ __launch_bounds__(256) void prep_kernel(const float* __restrict__ x,
                                                   const float* __restrict__ wq,
                                                   const float* __restrict__ wo,
                                                   const float* __restrict__ rel_pos,
                                                   unsigned short* __restrict__ xb,
                                                   unsigned short* __restrict__ wqb,
                                                   unsigned short* __restrict__ wob,
                                                   float* __restrict__ btab){
  const int bid = blockIdx.x;
  if (bid < 37632){
    int idx = bid*256 + threadIdx.x;               // 100352*96 threads, 4 ch each
    int token = idx / 96, j = idx - token*96;
    int b = token / 3136, rem = token - b*3136;
    int rr = rem / 56, cp = rem - rr*56;
    int p = rr >> 3, h = rr & 7, q = cp >> 3, w = cp & 7;
    int orow = ((b*8 + h)*8 + w)*49 + p*7 + q;
    float4 v = *(const float4*)(x + (size_t)idx*4);
    ushort4 o;
    o.x = f2bf(v.x); o.y = f2bf(v.y); o.z = f2bf(v.z); o.w = f2bf(v.w);
    *(ushort4*)(xb + (size_t)orow*384 + j*4) = o;
  } else if (bid < 37920){
    int idx = (bid - 37632)*256 + threadIdx.x;     // 73728 threads, 8 elems each
    const float* src;
    unsigned short* dst;
    int slot;
    if (idx < 55296){ slot = idx;         src = wq; dst = wqb + (size_t)idx*8; }
    else            { slot = idx - 55296; src = wo; dst = wob + (size_t)(idx-55296)*8; }
    int lane = slot & 63;
    int r = slot >> 6;
    int tj = r & 3; r >>= 2;
    int t = r % 12, bw = r / 12;                   // bw < 18 (qkv) or < 6 (out)
    int row = bw*64 + tj*16 + (lane & 15);
    int col = t*32 + (lane >> 4)*8;
    const float* s = src + (size_t)row*384 + col;
    float4 v1 = *(const float4*)(s);
    float4 v2 = *(const float4*)(s + 4);
    ushort4 o1, o2;
    o1.x=f2bf(v1.x); o1.y=f2bf(v1.y); o1.z=f2bf(v1.z); o1.w=f2bf(v1.w);
    o2.x=f2bf(v2.x); o2.y=f2bf(v2.y); o2.z=f2bf(v2.z); o2.w=f2bf(v2.w);
    *(ushort4*)(dst)     = o1;
    *(ushort4*)(dst + 4) = o2;
  } else {
    int idx = (bid - 37920)*256 + threadIdx.x;     // 12288 threads
    int head = idx >> 10, rem = idx & 1023;
    int fi = rem >> 6, lane = rem & 63;
    int ti = fi >> 2, tj = fi & 3;
    int qq = tj*16 + (lane & 15);
    int kb = ti*16 + (lane >> 4)*4;
    float4 v; float* vp = (float*)&v;
#pragma unroll
    for (int r=0; r<4; ++r){
      int kk = kb + r;
      float val;
      if (kk >= 49) val = -__builtin_inff();
      else if (qq >= 49) val = 0.f;
      else {
        int ip = qq/7, iq = qq - ip*7, jp = kk/7, jq = kk - jp*7;
        val = rel_pos[head*169 + (ip-jp+6)*13 + (iq-jq+6)] * 1.4426950408889634f;
      }
      vp[r] = val;
    }
    *(float4*)(btab + (size_t)idx*4) = v;
  }
}

// ---- 256x128 tile bf16 GEMM, B DIRECT-FROM-GLOBAL (fragment-major, L2-hot):
// LDS holds only A (triple-buffered, XOR-swizzled, ASYNC16) -> ds_read bytes
// per block-iter 48->32KB (the measured binding limit: 27% MfmaUtil == ds_read
// roofline). B-fragments: 4 coalesced b128/wave/iter into bfr[2][4] regs,
// issued AFTER the MFMA cluster (1.7-iter lead; vmcnt(8) at loop top drains
// exactly {stage(t), B(t)}).  Same-XCD A-panel block swizzle.
// EPI 0: q(*scale*log2e)/k/v bf16 [win][head][49][32].  EPI 1: fp32 un-windowed.
template<int EPI, int NBY>
__global__ __launch_bounds__(256) void gemm256(const unsigned short* __restrict__ A,
                                               const unsigned short* __restrict__ B,
                                               const float* __restrict__ bias,
                                               unsigned short* __restrict__ qo,
                                               unsigned short* __restrict__ ko,
                                               unsigned short* __restrict__ vo,
                                               float* __restrict__ out)
{
  constexpr int K = 384;
  constexpr int NT = 12;                    // K/32
  __shared__ unsigned short Al[3][256*32];  // 48 KiB total
  const int tid = threadIdx.x;
  const int lane = tid & 63, wid = tid >> 6;
  const int wr = wid >> 1, wc = wid & 1;
  const int l15 = lane & 15, kg = lane >> 4;
  const int swz = (l15 >> 1) & 3;                       // read-side chunk XOR
  const int cswz = (tid & 3) ^ ((tid >> 3) & 3);        // A source pre-swizzle

  // block swizzle: NBY n-blocks sharing one A-panel stay on one XCD
  const int n = blockIdx.x;
  const int xcd = n & 7, s = n >> 3;
  const int panel = s / NBY, nb = s - panel*NBY;
  const int bx = panel*8 + xcd, by = nb;

  const unsigned short* Ag = A + ((size_t)bx*256 + (tid>>2))*K + cswz*8;
  // fragment-major B panel for (by,wc): [12 t][4 tj][64 lane][8]
  const unsigned short* Bf = B + ((size_t)(by*2 + wc))*12*2048 + lane*8;

  f32x4 acc[8][4] = {};
  bf16x8 bfr[2][4];

#define STAGE(buf, kt) do { \
    ASYNC16(&Al[buf][wid*512],        Ag + (kt)*32); \
    ASYNC16(&Al[buf][wid*512 + 2048], Ag + (size_t)64*K  + (kt)*32); \
    ASYNC16(&Al[buf][wid*512 + 4096], Ag + (size_t)128*K + (kt)*32); \
    ASYNC16(&Al[buf][wid*512 + 6144], Ag + (size_t)192*K + (kt)*32); \
  } while(0)
#define LOADB(d, kt) do { \
    bfr[d][0] = *(const bf16x8*)(Bf + (kt)*2048); \
    bfr[d][1] = *(const bf16x8*)(Bf + (kt)*2048 + 512); \
    bfr[d][2] = *(const bf16x8*)(Bf + (kt)*2048 + 1024); \
    bfr[d][3] = *(const bf16x8*)(Bf + (kt)*2048 + 1536); \
  } while(0)

  // prologue issue order matters for the vmcnt ledger: S0(4) B0(4) S1(4) B1(4)
  STAGE(0,0); LOADB(0,0);
  STAGE(1,1); LOADB(1,1);

#pragma unroll
  for (int t = 0; t < NT; ++t){
    // top in-flight (oldest->newest): S(t)4, B(t)4, S(t+1)4, B(t+1)4.
    // vmcnt(8) drains S(t)+B(t); barrier additionally proves buffer (t+2)%3
    // free (read finished at t-1).
    if (t < NT-1) asm volatile("s_waitcnt vmcnt(8)\n\ts_barrier" ::: "memory");
    else          asm volatile("s_waitcnt vmcnt(0)\n\ts_barrier" ::: "memory");

    if (t + 2 < NT) STAGE((t+2)%3, t+2);

    const unsigned short* Ab = Al[t % 3];
    bf16x8 af[8];
#pragma unroll
    for (int ti=0; ti<8; ++ti)
      af[ti] = *(const bf16x8*)(Ab + (wr*128 + ti*16 + l15)*32 + (kg ^ swz)*8);

    __builtin_amdgcn_s_setprio(1);
#pragma unroll
    for (int ti=0; ti<8; ++ti)
#pragma unroll
      for (int tj=0; tj<4; ++tj)
        acc[ti][tj] = __builtin_amdgcn_mfma_f32_16x16x32_bf16(af[ti], bfr[t&1][tj], acc[ti][tj], 0,0,0);
    __builtin_amdgcn_s_setprio(0);

    // B(t+2) into the slot just freed (after MFMA consumed bfr[t&1])
    if (t + 2 < NT) LOADB(t&1, t+2);
  }
#undef STAGE
#undef LOADB

  const int rbase = bx*256 + wr*128 + kg*4;

  if (EPI == 0){
    const int t = by / 3;                          // block-uniform q/k/v select
    unsigned short* __restrict__ Pout = (t==0) ? qo : ((t==1) ? ko : vo);
    // q scale folds softmax 1/sqrt(d) AND log2(e) for exp2-softmax
    const float scale = (t==0) ? (0.17677669529663689f * 1.4426950408889634f) : 1.0f;
    const int cb = (by - t*3)*128 + wc*64;         // col base within 384
    int hoff[4]; float bvs[4];
#pragma unroll
    for (int tj=0; tj<4; ++tj){
      int colt = cb + tj*16;
      hoff[tj] = (colt>>5)*1568 + (colt&31) + l15; // head*49*32 + dd
      bvs[tj] = bias[by*128 + wc*64 + tj*16 + l15] * scale;
    }
#pragma unroll
    for (int ti=0; ti<8; ++ti){
#pragma unroll
      for (int r=0; r<4; ++r){
        int R = rbase + ti*16 + r;
        int win = R / 49, nn = R - win*49;
        size_t rowoff = (size_t)win*18816 + nn*32;
#pragma unroll
        for (int tj=0; tj<4; ++tj)
          Pout[rowoff + hoff[tj]] = f2bf(acc[ti][tj][r]*scale + bvs[tj]);
      }
    }
  } else {
    const int cbs = by*128 + wc*64;                // scalar col base
    float bv[4];
#pragma unroll
    for (int tj=0; tj<4; ++tj) bv[tj] = bias[cbs + tj*16 + l15];
#pragma unroll
    for (int ti=0; ti<8; ++ti){
#pragma unroll
      for (int r=0; r<4; ++r){
        int R = rbase + ti*16 + r;
        int win = R / 49, nn = R - win*49;
        int p = nn / 7, q = nn - p*7;
        int h = (win >> 3) & 7, w = win & 7;
        size_t tok = (size_t)(win >> 6)*3136 + (size_t)((p*8 + h)*56 + q*8 + w);
        float* __restrict__ orow = out + tok*384 + cbs + l15;
#pragma unroll
        for (int tj=0; tj<4; ++tj)
          orow[tj*16] = acc[ti][tj][r] + bv[tj];
      }
    }
  }
}

// ---- windowed attention, swapped-QK^T in-register softmax (R9-proven form). ----
__global__ __launch_bounds__(256) void attn_kernel(const unsigned short* __restrict__ q,
                                                   const unsigned short* __restrict__ k,
                                                   const unsigned short* __restrict__ v,
                                                   const float* __restrict__ btab,
                                                   unsigned short* __restrict__ ao)
{
  __shared__ unsigned short P[4][4096];   // per-wave 64x64 bf16, XOR-swizzled
  const int tid = threadIdx.x, lane = tid & 63, wid = tid >> 6;
  const int l15 = lane & 15, kg = lane >> 4;
  const int win = blockIdx.x / 3;
  const int head = (blockIdx.x % 3)*4 + wid;
  const size_t base = ((size_t)win*12 + head)*1568;   // 49*32
  const unsigned short* qb = q + base;
  const unsigned short* kb = k + base;
  const unsigned short* vb = v + base;
  const float* bt = btab + head*4096;

  // V fragments first (independent; latency hides under QK^T + softmax).
  bf16x8 vfk[2][2];
#pragma unroll
  for (int ks=0; ks<2; ++ks)
#pragma unroll
    for (int tjv=0; tjv<2; ++tjv)
#pragma unroll
      for (int e=0; e<8; ++e)
        vfk[ks][tjv][e] = (short)vb[(ks*32 + kg*8 + e)*32 + tjv*16 + l15];

  // S^T C-init = bias fragment (coalesced b128 per frag)
  f32x4 s[4][4];
#pragma unroll
  for (int ti=0; ti<4; ++ti)
#pragma unroll
    for (int tj=0; tj<4; ++tj)
      s[ti][tj] = *(const f32x4*)(bt + ((ti*4 + tj)*64 + lane)*4);

  bf16x8 kf[4], qf[4];
#pragma unroll
  for (int ti=0; ti<4; ++ti) kf[ti] = *(const bf16x8*)(kb + (ti*16+l15)*32 + kg*8);
#pragma unroll
  for (int tj=0; tj<4; ++tj) qf[tj] = *(const bf16x8*)(qb + (tj*16+l15)*32 + kg*8);

  __builtin_amdgcn_s_setprio(1);
#pragma unroll
  for (int ti=0; ti<4; ++ti)
#pragma unroll
    for (int tj=0; tj<4; ++tj)
      s[ti][tj] = __builtin_amdgcn_mfma_f32_16x16x32_bf16(kf[ti], qf[tj], s[ti][tj], 0,0,0);
  __builtin_amdgcn_s_setprio(0);

  // softmax: lane owns 4 q-rows (tj), 16 k-values each in-register.
  float rinv[4];
#pragma unroll
  for (int tj=0; tj<4; ++tj){
    float sum = 0.f;
#pragma unroll
    for (int ti=0; ti<4; ++ti)
#pragma unroll
      for (int r=0; r<4; ++r){
        float e = exp2f(s[ti][tj][r]);
        s[ti][tj][r] = e;
        sum += e;
      }
    sum += __shfl_xor(sum, 16);
    sum += __shfl_xor(sum, 32);
    rinv[tj] = __builtin_amdgcn_rcpf(sum);
  }

  // pack P (x rinv) as bf16 k-pairs -> swizzled LDS [q=64][k=64]
  unsigned short* Pl = P[wid];
  const unsigned swz = (unsigned)((l15 & 7) << 4);
#pragma unroll
  for (int tj=0; tj<4; ++tj){
    const float rv = rinv[tj];
    const unsigned rowb = (unsigned)((tj*16 + l15)*128);
#pragma unroll
    for (int ti=0; ti<4; ++ti){
      uint2 d;
      d.x = cvt_pk_bf16(s[ti][tj][0]*rv, s[ti][tj][1]*rv);
      d.y = cvt_pk_bf16(s[ti][tj][2]*rv, s[ti][tj][3]*rv);
      unsigned boff = (rowb + (unsigned)(ti*32 + kg*8)) ^ swz;
      *(uint2*)((char*)Pl + boff) = d;
    }
  }

  // O = P @ V
  f32x4 o[4][2] = {};
#pragma unroll
  for (int oti=0; oti<4; ++oti){
    bf16x8 pa[2];
#pragma unroll
    for (int ks=0; ks<2; ++ks){
      unsigned boff = ((unsigned)((oti*16+l15)*128 + ks*64 + kg*16)) ^ swz;
      pa[ks] = *(const bf16x8*)((char*)Pl + boff);
    }
    __builtin_amdgcn_s_setprio(1);
#pragma unroll
    for (int tjv=0; tjv<2; ++tjv){
      o[oti][tjv] = __builtin_amdgcn_mfma_f32_16x16x32_bf16(pa[0], vfk[0][tjv], o[oti][tjv], 0,0,0);
      o[oti][tjv] = __builtin_amdgcn_mfma_f32_16x16x32_bf16(pa[1], vfk[1][tjv], o[oti][tjv], 0,0,0);
    }
    __builtin_amdgcn_s_setprio(0);
  }

  // store rows < 49 (rinv already folded into P)
#pragma unroll
  for (int oti=0; oti<4; ++oti)
#pragma unroll
    for (int r=0; r<4; ++r){
      int row = oti*16 + kg*4 + r;
      if (row < 49){
        unsigned short* op = ao + ((size_t)win*49 + row)*384 + head*32 + l15;
        op[0]  = (unsigned short)cvt_pk_bf16(o[oti][0][r], o[oti][0][r]);
        op[16] = (unsigned short)cvt_pk_bf16(o[oti][1][r], o[oti][1][r]);
      }
    }
}

extern "C" void kernel_launch(void* const* d_in, const int* in_sizes, int n_in,
                              void* d_out, int out_size, void* d_ws, size_t ws_size,
                              hipStream_t stream)
{
  const float* x       = (const float*)d_in[0];   // 32*56*56*384
  const float* w_qkv   = (const float*)d_in[1];   // 1152*384
  const float* b_qkv   = (const float*)d_in[2];   // 1152
  const float* rel_pos = (const float*)d_in[3];   // 12*169
  const float* w_out   = (const float*)d_in[4];   // 384*384
  const float* b_out   = (const float*)d_in[5];   // 384
  float* out = (float*)d_out;                     // 100352*384

  char* ws = (char*)d_ws;
  unsigned short* wqb = (unsigned short*)ws;                  // 884736 B (frag-major)
  unsigned short* wob = (unsigned short*)(ws + 884736);       // 294912 B (frag-major)
  float* btab         = (float*)(ws + 884736 + 294912);       // 196608 B
  unsigned short* qws = (unsigned short*)(ws + 1376256);      // 38535168 elems
  unsigned short* kws = qws + 38535168;
  unsigned short* vws = kws + 38535168;
  unsigned short* xb  = vws + 38535168;   // x_bf during GEMM1, attn-out after
  unsigned short* ao  = xb;               // total ws ~309.7 MB

  prep_kernel<<<dim3(37968), dim3(256), 0, stream>>>(x, w_qkv, w_out, rel_pos,
                                                     xb, wqb, wob, btab);
  gemm256<0,9><<<dim3(3528), dim3(256), 0, stream>>>(xb, wqb, b_qkv, qws, kws, vws, nullptr);
  attn_kernel<<<dim3(6144), dim3(256), 0, stream>>>(qws, kws, vws, btab, ao);
  gemm256<1,3><<<dim3(1176), dim3(256), 0, stream>>>(ao, wob, b_out, nullptr, nullptr, nullptr, out);
}

// Round 15
// 306.636 us; speedup vs baseline: 1.1242x; 1.1242x over previous
//
#include <hip/hip_runtime.h>

typedef __attribute__((ext_vector_type(8))) short bf16x8;
typedef __attribute__((ext_vector_type(4))) float f32x4;

__device__ __forceinline__ unsigned short f2bf(float f){
  unsigned u = __builtin_bit_cast(unsigned, f);
  u += 0x7fffu + ((u >> 16) & 1u);
  return (unsigned short)(u >> 16);
}

__device__ __forceinline__ unsigned cvt_pk_bf16(float lo, float hi){
  unsigned r;
  asm("v_cvt_pk_bf16_f32 %0, %1, %2" : "=v"(r) : "v"(lo), "v"(hi));
  return r;
}

#define ASYNC16(ldsp, gp) __builtin_amdgcn_global_load_lds( \
    (const __attribute__((address_space(1))) unsigned int*)(gp), \
    (__attribute__((address_space(3))) unsigned int*)(ldsp), 16, 0, 0)

// ---- fused prep ----
// [0,37632): x fp32 -> bf16 window-ordered [win*49+n][384]
// [37632,37992): weights: Wqkv -> bf16 FRAGMENT-MAJOR keyed to the fused kernel
//   (slot r=(gi*12+t)*8+wt, gi=hg*3+m, wt=wid*2+tjj: elem =
//    Wqkv[m*384+hg*128+(wt>>1)*32+(wt&1)*16+(lane&15)][t*32+(lane>>4)*8+e]);
//   Wout -> bf16 row-major.   [37992,38040): btab fragment-major.
__global__ __launch_bounds__(256) void prep_kernel(const float* __restrict__ x,
                                                   const float* __restrict__ wq,
                                                   const float* __restrict__ wo,
                                                   const float* __restrict__ rel_pos,
                                                   unsigned short* __restrict__ xb,
                                                   unsigned short* __restrict__ wqb,
                                                   unsigned short* __restrict__ wob,
                                                   float* __restrict__ btab){
  const int bid = blockIdx.x;
  if (bid < 37632){
    int idx = bid*256 + threadIdx.x;               // 100352*96 threads, 4 ch each
    int token = idx / 96, j = idx - token*96;
    int b = token / 3136, rem = token - b*3136;
    int rr = rem / 56, cp = rem - rr*56;
    int p = rr >> 3, h = rr & 7, q = cp >> 3, w = cp & 7;
    int orow = ((b*8 + h)*8 + w)*49 + p*7 + q;
    float4 v = *(const float4*)(x + (size_t)idx*4);
    ushort4 o;
    o.x = f2bf(v.x); o.y = f2bf(v.y); o.z = f2bf(v.z); o.w = f2bf(v.w);
    *(ushort4*)(xb + (size_t)orow*384 + j*4) = o;
  } else if (bid < 37992){
    int idx = (bid - 37632)*256 + threadIdx.x;     // 92160 threads
    if (idx < 55296){                              // Wqkv frag-major, 8 elems
      int lane = idx & 63;
      int r = idx >> 6;                            // 0..863
      int wt = r & 7; int r2 = r >> 3;             // 0..107
      int t = r2 % 12, gi = r2 / 12;               // gi 0..8
      int hgp = gi / 3, m = gi - hgp*3;
      int row = m*384 + hgp*128 + (wt>>1)*32 + (wt&1)*16 + (lane & 15);
      int col = t*32 + (lane >> 4)*8;
      const float* s = wq + (size_t)row*384 + col;
      float4 v1 = *(const float4*)(s);
      float4 v2 = *(const float4*)(s + 4);
      ushort4 o1, o2;
      o1.x=f2bf(v1.x); o1.y=f2bf(v1.y); o1.z=f2bf(v1.z); o1.w=f2bf(v1.w);
      o2.x=f2bf(v2.x); o2.y=f2bf(v2.y); o2.z=f2bf(v2.z); o2.w=f2bf(v2.w);
      unsigned short* dst = wqb + (size_t)idx*8;
      *(ushort4*)(dst)     = o1;
      *(ushort4*)(dst + 4) = o2;
    } else {                                       // Wout row-major, 4 elems
      int k = idx - 55296;                         // 36864 threads
      float4 v = *(const float4*)(wo + (size_t)k*4);
      ushort4 o; o.x=f2bf(v.x); o.y=f2bf(v.y); o.z=f2bf(v.z); o.w=f2bf(v.w);
      *(ushort4*)(wob + (size_t)k*4) = o;
    }
  } else {
    int idx = (bid - 37992)*256 + threadIdx.x;     // 12288 threads
    int head = idx >> 10, rem = idx & 1023;
    int fi = rem >> 6, lane = rem & 63;
    int ti = fi >> 2, tj = fi & 3;
    int qq = tj*16 + (lane & 15);
    int kb = ti*16 + (lane >> 4)*4;
    float4 v; float* vp = (float*)&v;
#pragma unroll
    for (int r=0; r<4; ++r){
      int kk = kb + r;
      float val;
      if (kk >= 49) val = -__builtin_inff();
      else if (qq >= 49) val = 0.f;
      else {
        int ip = qq/7, iq = qq - ip*7, jp = kk/7, jq = kk - jp*7;
        val = rel_pos[head*169 + (ip-jp+6)*13 + (iq-jq+6)] * 1.4426950408889634f;
      }
      vp[r] = val;
    }
    *(float4*)(btab + (size_t)idx*4) = v;
  }
}

// ---- FUSED qkv-projection + windowed attention ----
// Block = (window, head-group of 4).  Wave w computes dd-cols w*32 of q/k/v
// for the group == exactly head (hg*4+w)'s attention inputs -> wave-private
// LDS, ZERO barriers.  A-frags direct from xb (contiguous window rows, shared
// by 12 waves via L1/L2; 3 blocks of a window are 2048 apart = same XCD).
// B-frags from frag-major Wqkv (coalesced, L2-hot).  q/k -> QK_lds[tok][q|k]
// (XOR-swizzled 128B rows); v -> VT_lds[dd][tok] via cvt_pk b64.  Attn body =
// R11-proven code with LDS b128 frag reads.  Rows 49..63 finite neighbor data
// (masked by btab -inf / P==0); last window clamped.
__global__ __launch_bounds__(256, 2) void fqa_kernel(const unsigned short* __restrict__ xb,
                                                     const unsigned short* __restrict__ Wf,
                                                     const float* __restrict__ bqkv,
                                                     const float* __restrict__ btab,
                                                     unsigned short* __restrict__ ao)
{
  __shared__ unsigned short QK[4][4096];   // [tok64][q32|k32], swizzled
  __shared__ unsigned short VT[4][2048];   // [dd32][tok64],   swizzled
  __shared__ unsigned short P [4][4096];   // [q64][k64],      swizzled
  const int tid = threadIdx.x, lane = tid & 63, wid = tid >> 6;
  const int l15 = lane & 15, kg = lane >> 4;
  const int win = blockIdx.x & 2047;
  const int hg  = blockIdx.x >> 11;              // 0..2
  const int head = hg*4 + wid;

  // ---- phase 1: qkv GEMM (M=64 window rows, N=32 own dd-cols, K=384) ----
  const unsigned short* ap[4];
#pragma unroll
  for (int ti=0; ti<4; ++ti){
    int rowg = win*49 + ti*16 + l15;
    if (rowg > 100351) rowg = 100351;            // finite clamp (last window)
    ap[ti] = xb + (size_t)rowg*384 + kg*8;
  }
  const unsigned short* bp[3][2];
#pragma unroll
  for (int m=0; m<3; ++m)
#pragma unroll
    for (int tjj=0; tjj<2; ++tjj)
      bp[m][tjj] = Wf + ((size_t)((hg*3 + m)*12)*8 + wid*2 + tjj)*512 + lane*8;

  f32x4 aq[4][2] = {}, ak[4][2] = {}, av[4][2] = {};
  bf16x8 afr[2][4], bq[2][2], bk[2][2], bv[2][2];

#define LOADA(d, t) do { \
    afr[d][0] = *(const bf16x8*)(ap[0] + (t)*32); \
    afr[d][1] = *(const bf16x8*)(ap[1] + (t)*32); \
    afr[d][2] = *(const bf16x8*)(ap[2] + (t)*32); \
    afr[d][3] = *(const bf16x8*)(ap[3] + (t)*32); \
  } while(0)
#define LOADB(d, t) do { \
    bq[d][0] = *(const bf16x8*)(bp[0][0] + (t)*4096); \
    bq[d][1] = *(const bf16x8*)(bp[0][1] + (t)*4096); \
    bk[d][0] = *(const bf16x8*)(bp[1][0] + (t)*4096); \
    bk[d][1] = *(const bf16x8*)(bp[1][1] + (t)*4096); \
    bv[d][0] = *(const bf16x8*)(bp[2][0] + (t)*4096); \
    bv[d][1] = *(const bf16x8*)(bp[2][1] + (t)*4096); \
  } while(0)

  LOADA(0, 0); LOADB(0, 0);
#pragma unroll
  for (int t=0; t<12; ++t){
    const int cur = t & 1;
    if (t < 11){ LOADA(cur^1, t+1); LOADB(cur^1, t+1); }
    __builtin_amdgcn_s_setprio(1);
#pragma unroll
    for (int ti=0; ti<4; ++ti)
#pragma unroll
      for (int tjj=0; tjj<2; ++tjj){
        aq[ti][tjj] = __builtin_amdgcn_mfma_f32_16x16x32_bf16(afr[cur][ti], bq[cur][tjj], aq[ti][tjj], 0,0,0);
        ak[ti][tjj] = __builtin_amdgcn_mfma_f32_16x16x32_bf16(afr[cur][ti], bk[cur][tjj], ak[ti][tjj], 0,0,0);
        av[ti][tjj] = __builtin_amdgcn_mfma_f32_16x16x32_bf16(afr[cur][ti], bv[cur][tjj], av[ti][tjj], 0,0,0);
      }
    __builtin_amdgcn_s_setprio(0);
  }
#undef LOADA
#undef LOADB

  // bias (q pre-scaled by 1/sqrt(d)*log2e for exp2-softmax)
  const float SCL = 0.17677669529663689f * 1.4426950408889634f;
  float biasq[2], biask[2], biasv[2];
#pragma unroll
  for (int tjj=0; tjj<2; ++tjj){
    int col = hg*128 + wid*32 + tjj*16 + l15;
    biasq[tjj] = bqkv[col] * SCL;
    biask[tjj] = bqkv[384 + col];
    biasv[tjj] = bqkv[768 + col];
  }

  // ---- phase 2: pack q,k -> QK_lds[tok][q|k] (b16, swizzled); v -> VT (b64) ----
  unsigned short* QKl = QK[wid];
  unsigned short* VTl = VT[wid];
#pragma unroll
  for (int ti=0; ti<4; ++ti){
#pragma unroll
    for (int tjj=0; tjj<2; ++tjj){
      const int cq = tjj*2 + (l15 >> 3);          // q chunks 0..3
      const int ck = 4 + tjj*2 + (l15 >> 3);      // k chunks 4..7
      const int sub = (l15 & 7)*2;
#pragma unroll
      for (int r=0; r<4; ++r){
        int tok = ti*16 + kg*4 + r;
        unsigned oq = (unsigned)(tok*128 + ((cq ^ (tok & 7)) << 4) + sub);
        unsigned ok = (unsigned)(tok*128 + ((ck ^ (tok & 7)) << 4) + sub);
        *(unsigned short*)((char*)QKl + oq) = f2bf(aq[ti][tjj][r]*SCL + biasq[tjj]);
        *(unsigned short*)((char*)QKl + ok) = f2bf(ak[ti][tjj][r] + biask[tjj]);
      }
      // v transposed: VT[dd][tok], 4 tokens packed as b64
      int dd = tjj*16 + l15;
      int cb = ti*2 + (kg >> 1);
      uint2 d;
      d.x = cvt_pk_bf16(av[ti][tjj][0] + biasv[tjj], av[ti][tjj][1] + biasv[tjj]);
      d.y = cvt_pk_bf16(av[ti][tjj][2] + biasv[tjj], av[ti][tjj][3] + biasv[tjj]);
      unsigned ov = (unsigned)(dd*128 + ((cb ^ (dd & 7)) << 4) + (kg & 1)*8);
      *(uint2*)((char*)VTl + ov) = d;
    }
  }

  // ---- phase 3: attention (R11-proven body; frags from wave-private LDS) ----
  const float* bt = btab + head*4096;
  f32x4 s[4][4];
#pragma unroll
  for (int ti=0; ti<4; ++ti)
#pragma unroll
    for (int tj=0; tj<4; ++tj)
      s[ti][tj] = *(const f32x4*)(bt + ((ti*4 + tj)*64 + lane)*4);

  bf16x8 kf[4], qf[4];
#pragma unroll
  for (int i=0; i<4; ++i){
    int tok = i*16 + l15;
    qf[i] = *(const bf16x8*)((char*)QKl + tok*128 + ((kg       ^ (tok & 7)) << 4));
    kf[i] = *(const bf16x8*)((char*)QKl + tok*128 + (((4 + kg) ^ (tok & 7)) << 4));
  }

  __builtin_amdgcn_s_setprio(1);
#pragma unroll
  for (int ti=0; ti<4; ++ti)
#pragma unroll
    for (int tj=0; tj<4; ++tj)
      s[ti][tj] = __builtin_amdgcn_mfma_f32_16x16x32_bf16(kf[ti], qf[tj], s[ti][tj], 0,0,0);
  __builtin_amdgcn_s_setprio(0);

  float rinv[4];
#pragma unroll
  for (int tj=0; tj<4; ++tj){
    float sum = 0.f;
#pragma unroll
    for (int ti=0; ti<4; ++ti)
#pragma unroll
      for (int r=0; r<4; ++r){
        float e = exp2f(s[ti][tj][r]);
        s[ti][tj][r] = e;
        sum += e;
      }
    sum += __shfl_xor(sum, 16);
    sum += __shfl_xor(sum, 32);
    rinv[tj] = __builtin_amdgcn_rcpf(sum);
  }

  unsigned short* Pl = P[wid];
  const unsigned swzP = (unsigned)((l15 & 7) << 4);
#pragma unroll
  for (int tj=0; tj<4; ++tj){
    const float rv = rinv[tj];
    const unsigned rowb = (unsigned)((tj*16 + l15)*128);
#pragma unroll
    for (int ti=0; ti<4; ++ti){
      uint2 d;
      d.x = cvt_pk_bf16(s[ti][tj][0]*rv, s[ti][tj][1]*rv);
      d.y = cvt_pk_bf16(s[ti][tj][2]*rv, s[ti][tj][3]*rv);
      unsigned boff = (rowb + (unsigned)(ti*32 + kg*8)) ^ swzP;
      *(uint2*)((char*)Pl + boff) = d;
    }
  }

  bf16x8 vfk[2][2];
#pragma unroll
  for (int ks=0; ks<2; ++ks)
#pragma unroll
    for (int tjv=0; tjv<2; ++tjv){
      int dd = tjv*16 + l15;
      vfk[ks][tjv] = *(const bf16x8*)((char*)VTl + dd*128 + (((ks*4 + kg) ^ (dd & 7)) << 4));
    }

  f32x4 o[4][2] = {};
#pragma unroll
  for (int oti=0; oti<4; ++oti){
    bf16x8 pa[2];
#pragma unroll
    for (int ks=0; ks<2; ++ks){
      unsigned boff = ((unsigned)((oti*16 + l15)*128 + ks*64 + kg*16)) ^ swzP;
      pa[ks] = *(const bf16x8*)((char*)Pl + boff);
    }
    __builtin_amdgcn_s_setprio(1);
#pragma unroll
    for (int tjv=0; tjv<2; ++tjv){
      o[oti][tjv] = __builtin_amdgcn_mfma_f32_16x16x32_bf16(pa[0], vfk[0][tjv], o[oti][tjv], 0,0,0);
      o[oti][tjv] = __builtin_amdgcn_mfma_f32_16x16x32_bf16(pa[1], vfk[1][tjv], o[oti][tjv], 0,0,0);
    }
    __builtin_amdgcn_s_setprio(0);
  }

#pragma unroll
  for (int oti=0; oti<4; ++oti)
#pragma unroll
    for (int r=0; r<4; ++r){
      int row = oti*16 + kg*4 + r;
      if (row < 49){
        unsigned short* op = ao + ((size_t)win*49 + row)*384 + head*32 + l15;
        op[0]  = (unsigned short)cvt_pk_bf16(o[oti][0][r], o[oti][0][r]);
        op[16] = (unsigned short)cvt_pk_bf16(o[oti][1][r], o[oti][1][r]);
      }
    }
}

// ---- 256x128 tile bf16 GEMM (R11-proven, used for out-proj only):
// A,B via ASYNC16 into XOR-k-chunk-swizzled LDS; triple-buffered single-barrier
// pipeline, counted vmcnt(6).  Same-XCD A-panel block swizzle. fp32 un-windowed.
template<int NBY>
__global__ __launch_bounds__(256) void gemm256(const unsigned short* __restrict__ A,
                                               const unsigned short* __restrict__ B,
                                               const float* __restrict__ bias,
                                               float* __restrict__ out)
{
  constexpr int K = 384;
  constexpr int NT = 12;
  __shared__ unsigned short Al[3][256*32];
  __shared__ unsigned short Bl[3][128*32];
  const int tid = threadIdx.x;
  const int lane = tid & 63, wid = tid >> 6;
  const int wr = wid >> 1, wc = wid & 1;
  const int l15 = lane & 15, kg = lane >> 4;
  const int swz = (l15 >> 1) & 3;
  const int cswz = (tid & 3) ^ ((tid >> 3) & 3);

  const int n = blockIdx.x;
  const int xcd = n & 7, s = n >> 3;
  const int panel = s / NBY, nb = s - panel*NBY;
  const int bx = panel*8 + xcd, by = nb;

  const unsigned short* Ag = A + ((size_t)bx*256 + (tid>>2))*K + cswz*8;
  const unsigned short* Bg = B + ((size_t)(by*128 + (tid>>2)))*K + cswz*8;

  f32x4 acc[8][4] = {};

#define STAGE(buf, kt) do { \
    ASYNC16(&Al[buf][wid*512],        Ag + (kt)*32); \
    ASYNC16(&Al[buf][wid*512 + 2048], Ag + (size_t)64*K  + (kt)*32); \
    ASYNC16(&Al[buf][wid*512 + 4096], Ag + (size_t)128*K + (kt)*32); \
    ASYNC16(&Al[buf][wid*512 + 6144], Ag + (size_t)192*K + (kt)*32); \
    ASYNC16(&Bl[buf][wid*512],        Bg + (kt)*32); \
    ASYNC16(&Bl[buf][wid*512 + 2048], Bg + (size_t)64*K  + (kt)*32); \
  } while(0)

  STAGE(0,0); STAGE(1,1);

#pragma unroll
  for (int t = 0; t < NT; ++t){
    if (t < NT-1) asm volatile("s_waitcnt vmcnt(6)\n\ts_barrier" ::: "memory");
    else          asm volatile("s_waitcnt vmcnt(0)\n\ts_barrier" ::: "memory");

    if (t + 2 < NT) STAGE((t+2)%3, t+2);

    const unsigned short* Ab = Al[t % 3];
    const unsigned short* Bb = Bl[t % 3];
    bf16x8 af[8], bfv[4];
#pragma unroll
    for (int ti=0; ti<8; ++ti)
      af[ti] = *(const bf16x8*)(Ab + (wr*128 + ti*16 + l15)*32 + (kg ^ swz)*8);
#pragma unroll
    for (int tj=0; tj<4; ++tj)
      bfv[tj] = *(const bf16x8*)(Bb + (wc*64 + tj*16 + l15)*32 + (kg ^ swz)*8);

    __builtin_amdgcn_s_setprio(1);
#pragma unroll
    for (int ti=0; ti<8; ++ti)
#pragma unroll
      for (int tj=0; tj<4; ++tj)
        acc[ti][tj] = __builtin_amdgcn_mfma_f32_16x16x32_bf16(af[ti], bfv[tj], acc[ti][tj], 0,0,0);
    __builtin_amdgcn_s_setprio(0);
  }
#undef STAGE

  const int rbase = bx*256 + wr*128 + kg*4;
  const int cbs = by*128 + wc*64;
  float bv[4];
#pragma unroll
  for (int tj=0; tj<4; ++tj) bv[tj] = bias[cbs + tj*16 + l15];
#pragma unroll
  for (int ti=0; ti<8; ++ti){
#pragma unroll
    for (int r=0; r<4; ++r){
      int R = rbase + ti*16 + r;
      int win = R / 49, nn = R - win*49;
      int p = nn / 7, q = nn - p*7;
      int h = (win >> 3) & 7, w = win & 7;
      size_t tok = (size_t)(win >> 6)*3136 + (size_t)((p*8 + h)*56 + q*8 + w);
      float* __restrict__ orow = out + tok*384 + cbs + l15;
#pragma unroll
      for (int tj=0; tj<4; ++tj)
        orow[tj*16] = acc[ti][tj][r] + bv[tj];
    }
  }
}

extern "C" void kernel_launch(void* const* d_in, const int* in_sizes, int n_in,
                              void* d_out, int out_size, void* d_ws, size_t ws_size,
                              hipStream_t stream)
{
  const float* x       = (const float*)d_in[0];   // 32*56*56*384
  const float* w_qkv   = (const float*)d_in[1];   // 1152*384
  const float* b_qkv   = (const float*)d_in[2];   // 1152
  const float* rel_pos = (const float*)d_in[3];   // 12*169
  const float* w_out   = (const float*)d_in[4];   // 384*384
  const float* b_out   = (const float*)d_in[5];   // 384
  float* out = (float*)d_out;                     // 100352*384

  char* ws = (char*)d_ws;
  unsigned short* wqb = (unsigned short*)ws;                  // 884736 B (frag-major)
  unsigned short* wob = (unsigned short*)(ws + 884736);       // 294912 B (row-major)
  float* btab         = (float*)(ws + 884736 + 294912);       // 196608 B
  unsigned short* xb  = (unsigned short*)(ws + 1376256);      // 38535168 elems
  unsigned short* ao  = xb + 38535168;                        // 38535168 elems
  // total ws use ~148 MB (q/k/v roundtrip eliminated)

  prep_kernel<<<dim3(38040), dim3(256), 0, stream>>>(x, w_qkv, w_out, rel_pos,
                                                     xb, wqb, wob, btab);
  fqa_kernel<<<dim3(6144), dim3(256), 0, stream>>>(xb, wqb, b_qkv, btab, ao);
  gemm256<3><<<dim3(1176), dim3(256), 0, stream>>>(ao, wob, b_out, out);
}

// Round 16
// 278.089 us; speedup vs baseline: 1.2396x; 1.1027x over previous
//
#include <hip/hip_runtime.h>

typedef __attribute__((ext_vector_type(8))) short bf16x8;
typedef __attribute__((ext_vector_type(4))) float f32x4;

__device__ __forceinline__ unsigned short f2bf(float f){
  unsigned u = __builtin_bit_cast(unsigned, f);
  u += 0x7fffu + ((u >> 16) & 1u);
  return (unsigned short)(u >> 16);
}

__device__ __forceinline__ unsigned cvt_pk_bf16(float lo, float hi){
  unsigned r;
  asm("v_cvt_pk_bf16_f32 %0, %1, %2" : "=v"(r) : "v"(lo), "v"(hi));
  return r;
}

#define ASYNC16(ldsp, gp) __builtin_amdgcn_global_load_lds( \
    (const __attribute__((address_space(1))) unsigned int*)(gp), \
    (__attribute__((address_space(3))) unsigned int*)(ldsp), 16, 0, 0)

// ---- fused prep (R15-proven) ----
// [0,37632): x fp32 -> bf16 window-ordered [win*49+n][384]
// [37632,37992): Wqkv -> bf16 FRAGMENT-MAJOR (fqa layout); Wout -> bf16 row-major
// [37992,38040): btab fragment-major, log2e-scaled, -inf mask k>=49.
__global__ __launch_bounds__(256) void prep_kernel(const float* __restrict__ x,
                                                   const float* __restrict__ wq,
                                                   const float* __restrict__ wo,
                                                   const float* __restrict__ rel_pos,
                                                   unsigned short* __restrict__ xb,
                                                   unsigned short* __restrict__ wqb,
                                                   unsigned short* __restrict__ wob,
                                                   float* __restrict__ btab){
  const int bid = blockIdx.x;
  if (bid < 37632){
    int idx = bid*256 + threadIdx.x;               // 100352*96 threads, 4 ch each
    int token = idx / 96, j = idx - token*96;
    int b = token / 3136, rem = token - b*3136;
    int rr = rem / 56, cp = rem - rr*56;
    int p = rr >> 3, h = rr & 7, q = cp >> 3, w = cp & 7;
    int orow = ((b*8 + h)*8 + w)*49 + p*7 + q;
    float4 v = *(const float4*)(x + (size_t)idx*4);
    ushort4 o;
    o.x = f2bf(v.x); o.y = f2bf(v.y); o.z = f2bf(v.z); o.w = f2bf(v.w);
    *(ushort4*)(xb + (size_t)orow*384 + j*4) = o;
  } else if (bid < 37992){
    int idx = (bid - 37632)*256 + threadIdx.x;     // 92160 threads
    if (idx < 55296){                              // Wqkv frag-major, 8 elems
      int lane = idx & 63;
      int r = idx >> 6;                            // 0..863
      int wt = r & 7; int r2 = r >> 3;             // 0..107
      int t = r2 % 12, gi = r2 / 12;               // gi 0..8
      int hgp = gi / 3, m = gi - hgp*3;
      int row = m*384 + hgp*128 + (wt>>1)*32 + (wt&1)*16 + (lane & 15);
      int col = t*32 + (lane >> 4)*8;
      const float* s = wq + (size_t)row*384 + col;
      float4 v1 = *(const float4*)(s);
      float4 v2 = *(const float4*)(s + 4);
      ushort4 o1, o2;
      o1.x=f2bf(v1.x); o1.y=f2bf(v1.y); o1.z=f2bf(v1.z); o1.w=f2bf(v1.w);
      o2.x=f2bf(v2.x); o2.y=f2bf(v2.y); o2.z=f2bf(v2.z); o2.w=f2bf(v2.w);
      unsigned short* dst = wqb + (size_t)idx*8;
      *(ushort4*)(dst)     = o1;
      *(ushort4*)(dst + 4) = o2;
    } else {                                       // Wout row-major, 4 elems
      int k = idx - 55296;                         // 36864 threads
      float4 v = *(const float4*)(wo + (size_t)k*4);
      ushort4 o; o.x=f2bf(v.x); o.y=f2bf(v.y); o.z=f2bf(v.z); o.w=f2bf(v.w);
      *(ushort4*)(wob + (size_t)k*4) = o;
    }
  } else {
    int idx = (bid - 37992)*256 + threadIdx.x;     // 12288 threads
    int head = idx >> 10, rem = idx & 1023;
    int fi = rem >> 6, lane = rem & 63;
    int ti = fi >> 2, tj = fi & 3;
    int qq = tj*16 + (lane & 15);
    int kb = ti*16 + (lane >> 4)*4;
    float4 v; float* vp = (float*)&v;
#pragma unroll
    for (int r=0; r<4; ++r){
      int kk = kb + r;
      float val;
      if (kk >= 49) val = -__builtin_inff();
      else if (qq >= 49) val = 0.f;
      else {
        int ip = qq/7, iq = qq - ip*7, jp = kk/7, jq = kk - jp*7;
        val = rel_pos[head*169 + (ip-jp+6)*13 + (iq-jq+6)] * 1.4426950408889634f;
      }
      vp[r] = val;
    }
    *(float4*)(btab + (size_t)idx*4) = v;
  }
}

// ---- FUSED qkv-projection + windowed attention, v2 ----
// Phase 1 now stages A (the shared 64x384 window panel) through LDS with the
// R4-proven ASYNC16 triple-buffer + counted-vmcnt pipeline (1 ASYNC16/thread/
// iter, 2-iter lead, XOR chunk swizzle) -- fixes R15's 1-iter reg-prefetch
// latency exposure AND the 4x per-wave A redundancy.  B stays direct-from-
// global frag-major (L2-hot, 6 coalesced b128/wave/iter, 1-iter lead).
// vmcnt ledger: iter t-1 issues B(t)[6] then A(t+1)[1] -> top-of-t vmcnt(1)
// drains {A(t), B(t)}, keeps A(t+1) in flight.
// P-LDS reuses QK's 8KB (QK dead once qf/kf are in regs; same-pointer alias
// orders the writes).  LDS 60KB -> 2 blocks/CU.
__global__ __launch_bounds__(256, 2) void fqa_kernel(const unsigned short* __restrict__ xb,
                                                     const unsigned short* __restrict__ Wf,
                                                     const float* __restrict__ bqkv,
                                                     const float* __restrict__ btab,
                                                     unsigned short* __restrict__ ao)
{
  __shared__ unsigned short Al[3][2048];   // A: 64 tok x 32 k per buf (12 KiB)
  __shared__ unsigned short QK[4][4096];   // [tok64][q32|k32] swizzled; reused as P
  __shared__ unsigned short VT[4][2048];   // [dd32][tok64] swizzled
  const int tid = threadIdx.x, lane = tid & 63, wid = tid >> 6;
  const int l15 = lane & 15, kg = lane >> 4;
  const int win = blockIdx.x & 2047;
  const int hg  = blockIdx.x >> 11;              // 0..2
  const int head = hg*4 + wid;

  // ---- phase 1: qkv GEMM (M=64 window rows, per-wave N=32 dd-cols, K=384) ----
  // A staging: thread covers window row tid>>2, chunk (tid&3)^(((tid>>3))&3)
  {
  }
  int srowg = win*49 + (tid >> 2);
  if (srowg > 100351) srowg = 100351;            // finite clamp (last window)
  const int cswz = (tid & 3) ^ ((tid >> 3) & 3);
  const unsigned short* AgS = xb + (size_t)srowg*384 + cswz*8;
  const int rswz = (l15 >> 1) & 3;               // read-side chunk XOR

  const unsigned short* bp[3][2];
#pragma unroll
  for (int m=0; m<3; ++m)
#pragma unroll
    for (int tjj=0; tjj<2; ++tjj)
      bp[m][tjj] = Wf + ((size_t)((hg*3 + m)*12)*8 + wid*2 + tjj)*512 + lane*8;

  f32x4 aq[4][2] = {}, ak[4][2] = {}, av[4][2] = {};
  bf16x8 bq[2][2], bk[2][2], bv[2][2];

#define STAGE_A(buf, t) ASYNC16(&Al[buf][wid*512], AgS + (t)*32)
#define LOADB(d, t) do { \
    bq[d][0] = *(const bf16x8*)(bp[0][0] + (t)*4096); \
    bq[d][1] = *(const bf16x8*)(bp[0][1] + (t)*4096); \
    bk[d][0] = *(const bf16x8*)(bp[1][0] + (t)*4096); \
    bk[d][1] = *(const bf16x8*)(bp[1][1] + (t)*4096); \
    bv[d][0] = *(const bf16x8*)(bp[2][0] + (t)*4096); \
    bv[d][1] = *(const bf16x8*)(bp[2][1] + (t)*4096); \
  } while(0)

  // prologue issue order: A(0)[1], B(0)[6], A(1)[1]  (8 in flight)
  STAGE_A(0, 0);
  LOADB(0, 0);
  STAGE_A(1, 1);

#pragma unroll
  for (int t = 0; t < 12; ++t){
    // drain {A(t), B(t)}; keep A(t+1) in flight; publish A(t) to all waves
    if (t < 11) asm volatile("s_waitcnt vmcnt(1)\n\ts_barrier" ::: "memory");
    else        asm volatile("s_waitcnt vmcnt(0)\n\ts_barrier" ::: "memory");

    if (t < 11)  LOADB((t+1)&1, t+1);          // B first (vmcnt ledger order)
    if (t < 10)  STAGE_A((t+2)%3, t+2);

    const unsigned short* Ab = Al[t % 3];
    bf16x8 afr[4];
#pragma unroll
    for (int ti=0; ti<4; ++ti)
      afr[ti] = *(const bf16x8*)(Ab + (ti*16 + l15)*32 + ((kg ^ rswz)*8));

    const int cur = t & 1;
    __builtin_amdgcn_s_setprio(1);
#pragma unroll
    for (int ti=0; ti<4; ++ti)
#pragma unroll
      for (int tjj=0; tjj<2; ++tjj){
        aq[ti][tjj] = __builtin_amdgcn_mfma_f32_16x16x32_bf16(afr[ti], bq[cur][tjj], aq[ti][tjj], 0,0,0);
        ak[ti][tjj] = __builtin_amdgcn_mfma_f32_16x16x32_bf16(afr[ti], bk[cur][tjj], ak[ti][tjj], 0,0,0);
        av[ti][tjj] = __builtin_amdgcn_mfma_f32_16x16x32_bf16(afr[ti], bv[cur][tjj], av[ti][tjj], 0,0,0);
      }
    __builtin_amdgcn_s_setprio(0);
  }
#undef STAGE_A
#undef LOADB

  // bias (q pre-scaled by 1/sqrt(d)*log2e for exp2-softmax)
  const float SCL = 0.17677669529663689f * 1.4426950408889634f;
  float biasq[2], biask[2], biasv[2];
#pragma unroll
  for (int tjj=0; tjj<2; ++tjj){
    int col = hg*128 + wid*32 + tjj*16 + l15;
    biasq[tjj] = bqkv[col] * SCL;
    biask[tjj] = bqkv[384 + col];
    biasv[tjj] = bqkv[768 + col];
  }

  // ---- phase 2: pack q,k -> QK_lds[tok][q|k] (b16, swizzled); v -> VT (b64) ----
  unsigned short* QKl = QK[wid];
  unsigned short* VTl = VT[wid];
#pragma unroll
  for (int ti=0; ti<4; ++ti){
#pragma unroll
    for (int tjj=0; tjj<2; ++tjj){
      const int cq = tjj*2 + (l15 >> 3);          // q chunks 0..3
      const int ck = 4 + tjj*2 + (l15 >> 3);      // k chunks 4..7
      const int sub = (l15 & 7)*2;
#pragma unroll
      for (int r=0; r<4; ++r){
        int tok = ti*16 + kg*4 + r;
        unsigned oq = (unsigned)(tok*128 + ((cq ^ (tok & 7)) << 4) + sub);
        unsigned ok = (unsigned)(tok*128 + ((ck ^ (tok & 7)) << 4) + sub);
        *(unsigned short*)((char*)QKl + oq) = f2bf(aq[ti][tjj][r]*SCL + biasq[tjj]);
        *(unsigned short*)((char*)QKl + ok) = f2bf(ak[ti][tjj][r] + biask[tjj]);
      }
      // v transposed: VT[dd][tok], 4 tokens packed as b64
      int dd = tjj*16 + l15;
      int cb = ti*2 + (kg >> 1);
      uint2 d;
      d.x = cvt_pk_bf16(av[ti][tjj][0] + biasv[tjj], av[ti][tjj][1] + biasv[tjj]);
      d.y = cvt_pk_bf16(av[ti][tjj][2] + biasv[tjj], av[ti][tjj][3] + biasv[tjj]);
      unsigned ov = (unsigned)(dd*128 + ((cb ^ (dd & 7)) << 4) + (kg & 1)*8);
      *(uint2*)((char*)VTl + ov) = d;
    }
  }

  // ---- phase 3: attention (R11-proven body; frags from wave-private LDS) ----
  const float* bt = btab + head*4096;
  f32x4 s[4][4];
#pragma unroll
  for (int ti=0; ti<4; ++ti)
#pragma unroll
    for (int tj=0; tj<4; ++tj)
      s[ti][tj] = *(const f32x4*)(bt + ((ti*4 + tj)*64 + lane)*4);

  bf16x8 kf[4], qf[4];
#pragma unroll
  for (int i=0; i<4; ++i){
    int tok = i*16 + l15;
    qf[i] = *(const bf16x8*)((char*)QKl + tok*128 + ((kg       ^ (tok & 7)) << 4));
    kf[i] = *(const bf16x8*)((char*)QKl + tok*128 + (((4 + kg) ^ (tok & 7)) << 4));
  }

  __builtin_amdgcn_s_setprio(1);
#pragma unroll
  for (int ti=0; ti<4; ++ti)
#pragma unroll
    for (int tj=0; tj<4; ++tj)
      s[ti][tj] = __builtin_amdgcn_mfma_f32_16x16x32_bf16(kf[ti], qf[tj], s[ti][tj], 0,0,0);
  __builtin_amdgcn_s_setprio(0);

  float rinv[4];
#pragma unroll
  for (int tj=0; tj<4; ++tj){
    float sum = 0.f;
#pragma unroll
    for (int ti=0; ti<4; ++ti)
#pragma unroll
      for (int r=0; r<4; ++r){
        float e = exp2f(s[ti][tj][r]);
        s[ti][tj][r] = e;
        sum += e;
      }
    sum += __shfl_xor(sum, 16);
    sum += __shfl_xor(sum, 32);
    rinv[tj] = __builtin_amdgcn_rcpf(sum);
  }

  // P reuses QK's LDS (QK dead: qf/kf already in regs; alias orders writes)
  unsigned short* Pl = QKl;
  const unsigned swzP = (unsigned)((l15 & 7) << 4);
#pragma unroll
  for (int tj=0; tj<4; ++tj){
    const float rv = rinv[tj];
    const unsigned rowb = (unsigned)((tj*16 + l15)*128);
#pragma unroll
    for (int ti=0; ti<4; ++ti){
      uint2 d;
      d.x = cvt_pk_bf16(s[ti][tj][0]*rv, s[ti][tj][1]*rv);
      d.y = cvt_pk_bf16(s[ti][tj][2]*rv, s[ti][tj][3]*rv);
      unsigned boff = (rowb + (unsigned)(ti*32 + kg*8)) ^ swzP;
      *(uint2*)((char*)Pl + boff) = d;
    }
  }

  bf16x8 vfk[2][2];
#pragma unroll
  for (int ks=0; ks<2; ++ks)
#pragma unroll
    for (int tjv=0; tjv<2; ++tjv){
      int dd = tjv*16 + l15;
      vfk[ks][tjv] = *(const bf16x8*)((char*)VTl + dd*128 + (((ks*4 + kg) ^ (dd & 7)) << 4));
    }

  f32x4 o[4][2] = {};
#pragma unroll
  for (int oti=0; oti<4; ++oti){
    bf16x8 pa[2];
#pragma unroll
    for (int ks=0; ks<2; ++ks){
      unsigned boff = ((unsigned)((oti*16 + l15)*128 + ks*64 + kg*16)) ^ swzP;
      pa[ks] = *(const bf16x8*)((char*)Pl + boff);
    }
    __builtin_amdgcn_s_setprio(1);
#pragma unroll
    for (int tjv=0; tjv<2; ++tjv){
      o[oti][tjv] = __builtin_amdgcn_mfma_f32_16x16x32_bf16(pa[0], vfk[0][tjv], o[oti][tjv], 0,0,0);
      o[oti][tjv] = __builtin_amdgcn_mfma_f32_16x16x32_bf16(pa[1], vfk[1][tjv], o[oti][tjv], 0,0,0);
    }
    __builtin_amdgcn_s_setprio(0);
  }

#pragma unroll
  for (int oti=0; oti<4; ++oti)
#pragma unroll
    for (int r=0; r<4; ++r){
      int row = oti*16 + kg*4 + r;
      if (row < 49){
        unsigned short* op = ao + ((size_t)win*49 + row)*384 + head*32 + l15;
        op[0]  = (unsigned short)cvt_pk_bf16(o[oti][0][r], o[oti][0][r]);
        op[16] = (unsigned short)cvt_pk_bf16(o[oti][1][r], o[oti][1][r]);
      }
    }
}

// ---- 256x128 tile bf16 GEMM (R11-proven, out-proj only) ----
template<int NBY>
__global__ __launch_bounds__(256) void gemm256(const unsigned short* __restrict__ A,
                                               const unsigned short* __restrict__ B,
                                               const float* __restrict__ bias,
                                               float* __restrict__ out)
{
  constexpr int K = 384;
  constexpr int NT = 12;
  __shared__ unsigned short Al[3][256*32];
  __shared__ unsigned short Bl[3][128*32];
  const int tid = threadIdx.x;
  const int lane = tid & 63, wid = tid >> 6;
  const int wr = wid >> 1, wc = wid & 1;
  const int l15 = lane & 15, kg = lane >> 4;
  const int swz = (l15 >> 1) & 3;
  const int cswz = (tid & 3) ^ ((tid >> 3) & 3);

  const int n = blockIdx.x;
  const int xcd = n & 7, s = n >> 3;
  const int panel = s / NBY, nb = s - panel*NBY;
  const int bx = panel*8 + xcd, by = nb;

  const unsigned short* Ag = A + ((size_t)bx*256 + (tid>>2))*K + cswz*8;
  const unsigned short* Bg = B + ((size_t)(by*128 + (tid>>2)))*K + cswz*8;

  f32x4 acc[8][4] = {};

#define STAGE(buf, kt) do { \
    ASYNC16(&Al[buf][wid*512],        Ag + (kt)*32); \
    ASYNC16(&Al[buf][wid*512 + 2048], Ag + (size_t)64*K  + (kt)*32); \
    ASYNC16(&Al[buf][wid*512 + 4096], Ag + (size_t)128*K + (kt)*32); \
    ASYNC16(&Al[buf][wid*512 + 6144], Ag + (size_t)192*K + (kt)*32); \
    ASYNC16(&Bl[buf][wid*512],        Bg + (kt)*32); \
    ASYNC16(&Bl[buf][wid*512 + 2048], Bg + (size_t)64*K  + (kt)*32); \
  } while(0)

  STAGE(0,0); STAGE(1,1);

#pragma unroll
  for (int t = 0; t < NT; ++t){
    if (t < NT-1) asm volatile("s_waitcnt vmcnt(6)\n\ts_barrier" ::: "memory");
    else          asm volatile("s_waitcnt vmcnt(0)\n\ts_barrier" ::: "memory");

    if (t + 2 < NT) STAGE((t+2)%3, t+2);

    const unsigned short* Ab = Al[t % 3];
    const unsigned short* Bb = Bl[t % 3];
    bf16x8 af[8], bfv[4];
#pragma unroll
    for (int ti=0; ti<8; ++ti)
      af[ti] = *(const bf16x8*)(Ab + (wr*128 + ti*16 + l15)*32 + (kg ^ swz)*8);
#pragma unroll
    for (int tj=0; tj<4; ++tj)
      bfv[tj] = *(const bf16x8*)(Bb + (wc*64 + tj*16 + l15)*32 + (kg ^ swz)*8);

    __builtin_amdgcn_s_setprio(1);
#pragma unroll
    for (int ti=0; ti<8; ++ti)
#pragma unroll
      for (int tj=0; tj<4; ++tj)
        acc[ti][tj] = __builtin_amdgcn_mfma_f32_16x16x32_bf16(af[ti], bfv[tj], acc[ti][tj], 0,0,0);
    __builtin_amdgcn_s_setprio(0);
  }
#undef STAGE

  const int rbase = bx*256 + wr*128 + kg*4;
  const int cbs = by*128 + wc*64;
  float bv[4];
#pragma unroll
  for (int tj=0; tj<4; ++tj) bv[tj] = bias[cbs + tj*16 + l15];
#pragma unroll
  for (int ti=0; ti<8; ++ti){
#pragma unroll
    for (int r=0; r<4; ++r){
      int R = rbase + ti*16 + r;
      int win = R / 49, nn = R - win*49;
      int p = nn / 7, q = nn - p*7;
      int h = (win >> 3) & 7, w = win & 7;
      size_t tok = (size_t)(win >> 6)*3136 + (size_t)((p*8 + h)*56 + q*8 + w);
      float* __restrict__ orow = out + tok*384 + cbs + l15;
#pragma unroll
      for (int tj=0; tj<4; ++tj)
        orow[tj*16] = acc[ti][tj][r] + bv[tj];
    }
  }
}

extern "C" void kernel_launch(void* const* d_in, const int* in_sizes, int n_in,
                              void* d_out, int out_size, void* d_ws, size_t ws_size,
                              hipStream_t stream)
{
  const float* x       = (const float*)d_in[0];   // 32*56*56*384
  const float* w_qkv   = (const float*)d_in[1];   // 1152*384
  const float* b_qkv   = (const float*)d_in[2];   // 1152
  const float* rel_pos = (const float*)d_in[3];   // 12*169
  const float* w_out   = (const float*)d_in[4];   // 384*384
  const float* b_out   = (const float*)d_in[5];   // 384
  float* out = (float*)d_out;                     // 100352*384

  char* ws = (char*)d_ws;
  unsigned short* wqb = (unsigned short*)ws;                  // 884736 B (frag-major)
  unsigned short* wob = (unsigned short*)(ws + 884736);       // 294912 B (row-major)
  float* btab         = (float*)(ws + 884736 + 294912);       // 196608 B
  unsigned short* xb  = (unsigned short*)(ws + 1376256);      // 38535168 elems
  unsigned short* ao  = xb + 38535168;                        // 38535168 elems

  prep_kernel<<<dim3(38040), dim3(256), 0, stream>>>(x, w_qkv, w_out, rel_pos,
                                                     xb, wqb, wob, btab);
  fqa_kernel<<<dim3(6144), dim3(256), 0, stream>>>(xb, wqb, b_qkv, btab, ao);
  gemm256<3><<<dim3(1176), dim3(256), 0, stream>>>(ao, wob, b_out, out);
}